// Round 6
// baseline (370.572 us; speedup 1.0000x reference)
//
#include <hip/hip_runtime.h>
#include <math.h>

// Problem constants
#define BROWS 16384
#define N0    2048
#define NCLS  12
#define NCLU  24
#define NDIM  4
#define NCOL  348          // 12 + 288 + 48
#define NPAD  384          // padded fused-column count (24 col-tiles of 16)
#define NTILE 24           // NPAD/16

// Output offsets (floats): y0 [B,12] | y1_sel [B,24] | y2_sel [B,4] | Plc [B,24,12]
#define OUT0_OFF 0
#define OUT1_OFF (BROWS * NCLS)
#define OUT2_OFF (OUT1_OFF + BROWS * NCLU)
#define OUT3_OFF (OUT2_OFF + BROWS * NDIM)

typedef __attribute__((ext_vector_type(8))) short bf16x8;
typedef __attribute__((ext_vector_type(4))) float f32x4;
typedef unsigned short ushort_t;

// ---------------------------------------------------------------------------
// bf16 helpers — RNE split (bit-identical to the passing Round-2 numerics)
// ---------------------------------------------------------------------------
__device__ __forceinline__ unsigned short f2bf(float f) {   // RNE
    unsigned u = __float_as_uint(f);
    u += 0x7fffu + ((u >> 16) & 1u);
    return (unsigned short)(u >> 16);
}
__device__ __forceinline__ float bf2f(unsigned short h) {
    return __uint_as_float(((unsigned)h) << 16);
}
__device__ __forceinline__ void cvt8(float4 a, float4 b, bf16x8& h, bf16x8& l) {
    float f[8] = {a.x, a.y, a.z, a.w, b.x, b.y, b.z, b.w};
    #pragma unroll
    for (int i = 0; i < 8; ++i) {
        unsigned short hi = f2bf(f[i]);
        h[i] = (short)hi;
        l[i] = (short)f2bf(f[i] - bf2f(hi));
    }
}

__device__ __forceinline__ void load_lds16(const void* g, void* l) {
    __builtin_amdgcn_global_load_lds((const __attribute__((address_space(1))) void*)g,
                                     (__attribute__((address_space(3))) void*)l, 16, 0, 0);
}

__device__ __forceinline__ float fused_w(const float* __restrict__ W_fc,
                                         const float* __restrict__ W_bin,
                                         const float* __restrict__ W_res,
                                         int col, int d) {
    float w = 0.0f;
    if (col < NCLS) {
        w = W_fc[d * NCLS + col];
    } else if (col < 12 + NCLU * NCLS) {
        int jj = col - 12;
        int k = jj / NCLS, c = jj - k * NCLS;
        w = W_bin[((size_t)c * N0 + d) * NCLU + k];
    } else if (col < NCOL) {
        int jj = col - 300;
        int n = jj / NCLS, c = jj - n * NCLS;
        w = W_res[((size_t)c * N0 + d) * NDIM + n];
    }
    return w;
}

// ---------------------------------------------------------------------------
// Kernel 1: repack fused weights into MFMA-fragment streaming order.
//   Bp{h,l}[((J*64 + kb)*64 + lane)*8 + i] = W[col = J*16 + (lane&15)]
//                                             [k  = kb*32 + (lane>>4)*8 + i]
// ---------------------------------------------------------------------------
__global__ void jcp_repack3(const float* __restrict__ W_fc, const float* __restrict__ b_fc,
                            const float* __restrict__ W_bin, const float* __restrict__ b_bin,
                            const float* __restrict__ W_res, const float* __restrict__ b_res,
                            ushort_t* __restrict__ Bph, ushort_t* __restrict__ Bpl,
                            float* __restrict__ bias) {
    int t = blockIdx.x * 256 + threadIdx.x;          // 0 .. 98303
    if (t >= NTILE * 64 * 64) return;
    const int lane = t & 63;
    const int kb   = (t >> 6) & 63;
    const int J    = t >> 12;
    const int col  = J * 16 + (lane & 15);
    const int k0   = kb * 32 + (lane >> 4) * 8;

    bf16x8 h, l;
    #pragma unroll
    for (int i = 0; i < 8; ++i) {
        float w = fused_w(W_fc, W_bin, W_res, col, k0 + i);
        unsigned short hi = f2bf(w);
        h[i] = (short)hi;
        l[i] = (short)f2bf(w - bf2f(hi));
    }
    *(bf16x8*)(Bph + (size_t)t * 8) = h;
    *(bf16x8*)(Bpl + (size_t)t * 8) = l;

    if (t < NPAD) {
        int jb = t;
        float bv = 0.0f;
        if (jb < NCLS) {
            bv = b_fc[jb];
        } else if (jb < 12 + NCLU * NCLS) {
            int jj = jb - 12;
            int k = jj / NCLS, c = jj - k * NCLS;
            bv = b_bin[c * NCLU + k];
        } else if (jb < NCOL) {
            int jj = jb - 300;
            int n = jj / NCLS, c = jj - n * NCLS;
            bv = b_res[c * NDIM + n];
        }
        bias[jb] = bv;
    }
}

// ---------------------------------------------------------------------------
// Kernel 1b: pre-convert x -> Xp. Record (row,kb) = 128 B:
//   shorts [0..31]  = hi of x[row][kb*32 .. +31]  (4 chunks of 8)
//   shorts [32..63] = lo                           (4 chunks of 8)
// Thread t: rec = t>>2, chunk c = t&3. Fully coalesced read and write.
// ---------------------------------------------------------------------------
__global__ __launch_bounds__(256) void jcp_cvtx(const float* __restrict__ x,
                                                ushort_t* __restrict__ Xp) {
    const int t = blockIdx.x * 256 + threadIdx.x;   // 0 .. 4194303
    const int rec = t >> 2;                         // row*64 + kb
    const int c   = t & 3;
    const float* src = x + (size_t)rec * 32 + c * 8;   // rec*32 == row*2048 + kb*32
    float4 a = *(const float4*)(src);
    float4 b = *(const float4*)(src + 4);
    bf16x8 h, l;
    cvt8(a, b, h, l);
    ushort_t* dst = Xp + (size_t)rec * 64;
    *(bf16x8*)(dst + c * 8) = h;
    *(bf16x8*)(dst + 32 + c * 8) = l;
}

// ---------------------------------------------------------------------------
// Kernel 2 (primary): split-bf16 MFMA GEMM v5 — no in-loop conversion.
//   Grid (4, 256), block 256 thr = 4 waves, tile 64 rows x 96 cols.
//   A: pre-converted bf16 hi/lo DMA'd to LDS (dbuf 2x8KB), chunk swizzle
//      slot = chunk ^ (row&7) applied on the DMA *source* address.
//   B: single-buffered regs from pre-swizzled fragment layout (coalesced).
// ---------------------------------------------------------------------------
__global__ __launch_bounds__(256, 4) void jcp_gemm5(const ushort_t* __restrict__ Xp,
                                                    const ushort_t* __restrict__ Bph,
                                                    const ushort_t* __restrict__ Bpl,
                                                    const float* __restrict__ bias,
                                                    float* __restrict__ Y) {
    __shared__ __attribute__((aligned(16))) ushort_t Lx[2][4096];  // 64 rows x 64 shorts

    const int tid  = threadIdx.x;
    const int wid  = tid >> 6;
    const int lane = tid & 63;
    const int quad = lane >> 4;
    const int l16  = lane & 15;
    const int wrow = (wid & 1) * 32;
    const int wct  = (wid >> 1) * 3;
    const int rbase = blockIdx.y * 64;
    const int jbase = blockIdx.x * 96;

    // --- DMA: 2 insts/wave, each 8 rows x 8 chunk-slots (1 KB) ---
    const int r8   = lane >> 3;               // row within 8-group
    const int cpos = lane & 7;                // dest chunk slot
    const int cs   = cpos ^ r8;               // source chunk (swizzle)
    const ushort_t* g0 = Xp + ((size_t)(rbase + wid * 16 + r8) * 64) * 64 + cs * 8;
    const ushort_t* g1 = Xp + ((size_t)(rbase + wid * 16 + 8 + r8) * 64) * 64 + cs * 8;
    const int d0 = (wid * 16) * 64;           // dest base (shorts) within buffer
    const int d1 = (wid * 16 + 8) * 64;

    // --- fragment read offsets (shorts) ---
    const int rm = l16 & 7;
    const int sh = quad ^ rm;                 // hi slot
    const int sl = (4 + quad) ^ rm;           // lo slot
    const int ro0 = (wrow + l16) * 64;
    const int ro1 = (wrow + 16 + l16) * 64;

    // --- B per-lane pointers, fragment-order arrays ---
    const ushort_t* pBh = Bph + (size_t)lane * 8;
    const ushort_t* pBl = Bpl + (size_t)lane * 8;
    int Jt[3];
    #pragma unroll
    for (int j = 0; j < 3; ++j) Jt[j] = (jbase / 16 + wct + j) * 32768;

    f32x4 acc[2][3];
    #pragma unroll
    for (int i = 0; i < 2; ++i)
        #pragma unroll
        for (int j = 0; j < 3; ++j)
            acc[i][j] = f32x4{0.f, 0.f, 0.f, 0.f};

    // stage it=0 into buf 0
    load_lds16(g0, &Lx[0][d0]);
    load_lds16(g1, &Lx[0][d1]);
    __syncthreads();

    int p = 0;
    for (int it = 0; it < 64; ++it) {
        // async-stage it+1 first (max overlap)
        if (it < 63) {
            load_lds16(g0 + (it + 1) * 64, &Lx[p ^ 1][d0]);
            load_lds16(g1 + (it + 1) * 64, &Lx[p ^ 1][d1]);
        }
        // B fragments (single-buffered, L2-resident, coalesced)
        bf16x8 bh[3], bl[3];
        #pragma unroll
        for (int j = 0; j < 3; ++j) {
            bh[j] = *(const bf16x8*)(pBh + Jt[j] + it * 512);
            bl[j] = *(const bf16x8*)(pBl + Jt[j] + it * 512);
        }
        // A fragments straight from LDS (already bf16 hi/lo)
        bf16x8 Ah[2], Al[2];
        Ah[0] = *(const bf16x8*)&Lx[p][ro0 + sh * 8];
        Al[0] = *(const bf16x8*)&Lx[p][ro0 + sl * 8];
        Ah[1] = *(const bf16x8*)&Lx[p][ro1 + sh * 8];
        Al[1] = *(const bf16x8*)&Lx[p][ro1 + sl * 8];

        // 18 MFMAs: per-accumulator order hh -> lh -> hl (R2-identical)
        #pragma unroll
        for (int j = 0; j < 3; ++j)
            #pragma unroll
            for (int i = 0; i < 2; ++i) {
                acc[i][j] = __builtin_amdgcn_mfma_f32_16x16x32_bf16(Ah[i], bh[j], acc[i][j], 0, 0, 0);
                acc[i][j] = __builtin_amdgcn_mfma_f32_16x16x32_bf16(Al[i], bh[j], acc[i][j], 0, 0, 0);
                acc[i][j] = __builtin_amdgcn_mfma_f32_16x16x32_bf16(Ah[i], bl[j], acc[i][j], 0, 0, 0);
            }
        __syncthreads();   // drains DMA (vmcnt 0) + guards buffer reuse
        p ^= 1;
    }

    // Epilogue: C/D layout col = lane&15, row = quad*4 + reg
    #pragma unroll
    for (int j = 0; j < 3; ++j) {
        const int col = jbase + wct * 16 + 16 * j + l16;
        const float bj = bias[col];
        #pragma unroll
        for (int i = 0; i < 2; ++i) {
            float* yp = Y + (size_t)(rbase + wrow + i * 16 + quad * 4) * NPAD + col;
            yp[0 * NPAD] = acc[i][j][0] + bj;
            yp[1 * NPAD] = acc[i][j][1] + bj;
            yp[2 * NPAD] = acc[i][j][2] + bj;
            yp[3 * NPAD] = acc[i][j][3] + bj;
        }
    }
}

// ---------------------------------------------------------------------------
// Kernel 2 (fallback, ws too small): R5 GEMM with in-loop cvt — bit-identical.
// ---------------------------------------------------------------------------
__global__ __launch_bounds__(256, 4) void jcp_gemm4(const float* __restrict__ x,
                                                    const ushort_t* __restrict__ Bph,
                                                    const ushort_t* __restrict__ Bpl,
                                                    const float* __restrict__ bias,
                                                    float* __restrict__ Y) {
    __shared__ float Lx[2 * 2048];

    const int tid  = threadIdx.x;
    const int wid  = tid >> 6;
    const int lane = tid & 63;
    const int quad = lane >> 4;
    const int l16  = lane & 15;
    const int wrow = (wid & 1) * 32;
    const int wct  = (wid >> 1) * 3;
    const int rbase = blockIdx.y * 64;
    const int jbase = blockIdx.x * 96;

    const int dr = lane >> 3;
    const int dc = (lane & 7) ^ dr;
    const float* gsrc0 = x + (size_t)(rbase + 8 * (2 * wid) + dr) * N0 + dc * 4;
    const float* gsrc1 = x + (size_t)(rbase + 8 * (2 * wid + 1) + dr) * N0 + dc * 4;
    const int ldst0 = (2 * wid) * 256;
    const int ldst1 = (2 * wid + 1) * 256;

    const int s = l16 & 7;
    const int pos1 = (2 * quad) ^ s;
    const int o1 = pos1 * 4;
    const int o2 = (pos1 ^ 1) * 4;
    const int ro0 = (wrow + l16) * 32;
    const int ro1 = (wrow + 16 + l16) * 32;

    const ushort_t* pBh = Bph + (size_t)lane * 8;
    const ushort_t* pBl = Bpl + (size_t)lane * 8;
    int Jt[3];
    #pragma unroll
    for (int j = 0; j < 3; ++j) Jt[j] = (jbase / 16 + wct + j) * 32768;

    f32x4 acc[2][3];
    #pragma unroll
    for (int i = 0; i < 2; ++i)
        #pragma unroll
        for (int j = 0; j < 3; ++j)
            acc[i][j] = f32x4{0.f, 0.f, 0.f, 0.f};

    load_lds16(gsrc0, &Lx[ldst0]);
    load_lds16(gsrc1, &Lx[ldst1]);
    __syncthreads();

    int p = 0;
    for (int it = 0; it < 64; ++it) {
        bf16x8 bh[3], bl[3];
        #pragma unroll
        for (int j = 0; j < 3; ++j) {
            bh[j] = *(const bf16x8*)(pBh + Jt[j] + it * 512);
            bl[j] = *(const bf16x8*)(pBl + Jt[j] + it * 512);
        }
        if (it < 63) {
            load_lds16(gsrc0 + (it + 1) * 32, &Lx[(p ^ 1) * 2048 + ldst0]);
            load_lds16(gsrc1 + (it + 1) * 32, &Lx[(p ^ 1) * 2048 + ldst1]);
        }
        const int pb = p * 2048;
        float4 f0a = *(const float4*)&Lx[pb + ro0 + o1];
        float4 f0b = *(const float4*)&Lx[pb + ro0 + o2];
        float4 f1a = *(const float4*)&Lx[pb + ro1 + o1];
        float4 f1b = *(const float4*)&Lx[pb + ro1 + o2];
        bf16x8 Ah[2], Al[2];
        cvt8(f0a, f0b, Ah[0], Al[0]);
        cvt8(f1a, f1b, Ah[1], Al[1]);

        #pragma unroll
        for (int j = 0; j < 3; ++j)
            #pragma unroll
            for (int i = 0; i < 2; ++i) {
                acc[i][j] = __builtin_amdgcn_mfma_f32_16x16x32_bf16(Ah[i], bh[j], acc[i][j], 0, 0, 0);
                acc[i][j] = __builtin_amdgcn_mfma_f32_16x16x32_bf16(Al[i], bh[j], acc[i][j], 0, 0, 0);
                acc[i][j] = __builtin_amdgcn_mfma_f32_16x16x32_bf16(Ah[i], bl[j], acc[i][j], 0, 0, 0);
            }
        __syncthreads();
        p ^= 1;
    }

    #pragma unroll
    for (int j = 0; j < 3; ++j) {
        const int col = jbase + wct * 16 + 16 * j + l16;
        const float bj = bias[col];
        #pragma unroll
        for (int i = 0; i < 2; ++i) {
            float* yp = Y + (size_t)(rbase + wrow + i * 16 + quad * 4) * NPAD + col;
            yp[0 * NPAD] = acc[i][j][0] + bj;
            yp[1 * NPAD] = acc[i][j][1] + bj;
            yp[2 * NPAD] = acc[i][j][2] + bj;
            yp[3 * NPAD] = acc[i][j][3] + bj;
        }
    }
}

// ---------------------------------------------------------------------------
// Kernel 3: head. Block = 256 thr = 16 rows x 16 lanes (lane = class).
// ---------------------------------------------------------------------------
#define LROW 388   // padded LDS row stride (floats)

__global__ __launch_bounds__(256) void jcp_head3(const float* __restrict__ Y,
                                                 float* __restrict__ out) {
    __shared__ float Ly[16 * LROW];
    const int tid = threadIdx.x;
    const int r0  = blockIdx.x * 16;

    #pragma unroll
    for (int jj = 0; jj < 6; ++jj) {
        int f = tid + jj * 256;
        int row = f / 96, c4 = f - row * 96;
        float4 v = *(const float4*)(Y + (size_t)(r0 + row) * NPAD + c4 * 4);
        *(float4*)&Ly[row * LROW + c4 * 4] = v;
    }
    __syncthreads();

    const int grp = tid >> 4;
    const int c   = tid & 15;
    const bool on = (c < NCLS);
    const int r   = r0 + grp;
    const float* y = &Ly[grp * LROW];

    float y0c = on ? y[c] : -INFINITY;
    float m0 = y0c;
    #pragma unroll
    for (int m = 8; m >= 1; m >>= 1) m0 = fmaxf(m0, __shfl_xor(m0, m, 16));
    float e0 = on ? expf(y0c - m0) : 0.0f;
    float s0 = e0;
    #pragma unroll
    for (int m = 8; m >= 1; m >>= 1) s0 += __shfl_xor(s0, m, 16);
    const float Pc = e0 / s0;

    float v[NCLU];
    float mc = -INFINITY;
    #pragma unroll
    for (int k = 0; k < NCLU; ++k) {
        v[k] = y[12 + k * NCLS + c];
        mc = fmaxf(mc, v[k]);
    }
    float sc = 0.0f;
    #pragma unroll
    for (int k = 0; k < NCLU; ++k) sc += expf(v[k] - mc);
    const float rs = Pc / sc;

    float y2c[NDIM];
    #pragma unroll
    for (int n = 0; n < NDIM; ++n) y2c[n] = y[300 + n * NCLS + c];

    float best = -INFINITY;
    int bk = 0;
    float* lrow = &Ly[grp * LROW];
    #pragma unroll
    for (int k = 0; k < NCLU; ++k) {
        const float p = expf(v[k] - mc) * rs;
        if (on) lrow[k * NCLS + c] = p;
        if (p > best) { best = p; bk = k; }
    }
    int flat = bk * NCLS + c;
    if (!on) { best = -INFINITY; flat = 1 << 30; }

    #pragma unroll
    for (int m = 8; m >= 1; m >>= 1) {
        const float op = __shfl_xor(best, m, 16);
        const int   of = __shfl_xor(flat, m, 16);
        if (op > best || (op == best && of < flat)) { best = op; flat = of; }
    }
    const int ic = flat % NCLS;

    if (on) out[OUT0_OFF + (size_t)r * NCLS + c] = y0c;
    if (c == ic) {
        float* o1 = out + OUT1_OFF + (size_t)r * NCLU;
        #pragma unroll
        for (int k = 0; k < NCLU; ++k) o1[k] = v[k];
        float* o2 = out + OUT2_OFF + (size_t)r * NDIM;
        #pragma unroll
        for (int n = 0; n < NDIM; ++n) o2[n] = y2c[n];
    }

    __syncthreads();
    #pragma unroll
    for (int jj = 0; jj < 5; ++jj) {
        int f = tid + jj * 256;
        if (f < 1152) {
            int row = f / 72, c4 = f - row * 72;
            *(float4*)(out + OUT3_OFF + (size_t)(r0 + row) * (NCLU * NCLS) + c4 * 4) =
                *(float4*)&Ly[row * LROW + c4 * 4];
        }
    }
}

// ---------------------------------------------------------------------------
extern "C" void kernel_launch(void* const* d_in, const int* in_sizes, int n_in,
                              void* d_out, int out_size, void* d_ws, size_t ws_size,
                              hipStream_t stream) {
    const float* x     = (const float*)d_in[0];
    const float* W_fc  = (const float*)d_in[1];
    const float* b_fc  = (const float*)d_in[2];
    const float* W_bin = (const float*)d_in[3];
    const float* b_bin = (const float*)d_in[4];
    const float* W_res = (const float*)d_in[5];
    const float* b_res = (const float*)d_in[6];
    float* out = (float*)d_out;

    // ws layout (shorts / floats)
    const size_t BP = (size_t)NTILE * 64 * 64 * 8;         // 786432 shorts per B array
    ushort_t* Bph  = (ushort_t*)d_ws;
    ushort_t* Bpl  = Bph + BP;
    float*    bias = (float*)(Bpl + BP);
    float*    Yb   = bias + NPAD;
    ushort_t* Xp   = (ushort_t*)(Yb + (size_t)BROWS * NPAD);  // 16384*64 records x 64 shorts
    const size_t need = (size_t)((char*)(Xp + (size_t)BROWS * 64 * 64) - (char*)d_ws);

    jcp_repack3<<<384, 256, 0, stream>>>(W_fc, b_fc, W_bin, b_bin, W_res, b_res,
                                         Bph, Bpl, bias);
    dim3 grid(NPAD / 96, BROWS / 64);   // (4, 256)
    if (ws_size >= need) {
        jcp_cvtx<<<BROWS * 64 * 4 / 256, 256, 0, stream>>>(x, Xp);
        jcp_gemm5<<<grid, 256, 0, stream>>>(Xp, Bph, Bpl, bias, Yb);
    } else {
        jcp_gemm4<<<grid, 256, 0, stream>>>(x, Bph, Bpl, bias, Yb);
    }
    jcp_head3<<<BROWS / 16, 256, 0, stream>>>(Yb, out);
}